// Round 9
// baseline (272.464 us; speedup 1.0000x reference)
//
#include <hip/hip_runtime.h>

// B=16, C=256, HEADS=4, d=64, N=W*H=1024
constexpr int Bb  = 16;
constexpr int Cch = 256;
constexpr int NH  = 4;
constexpr int Dh  = 64;
constexpr int Nn  = 1024;

typedef _Float16 f16;
typedef __attribute__((ext_vector_type(8))) _Float16 f16x8;
typedef __attribute__((ext_vector_type(4))) _Float16 f16x4;
typedef __attribute__((ext_vector_type(4))) float    f32x4;

// ---------------------------------------------------------------------------
// QKV projection GEMM, fp16 MFMA + rel_t slice (unchanged from R8).
// grid = (8, 7, 16), block = 256.
// ---------------------------------------------------------------------------
__global__ __launch_bounds__(256) void gemm_qkv(
    const float* __restrict__ x,
    const float* __restrict__ Wq, const float* __restrict__ Wk,
    const float* __restrict__ Wv,
    const float* __restrict__ bq, const float* __restrict__ bk,
    const float* __restrict__ bv,
    const float* __restrict__ rel_h, const float* __restrict__ rel_w,
    f16* __restrict__ qt, f16* __restrict__ kt, f16* __restrict__ vb,
    f16* __restrict__ rel_t)
{
    const int bx   = blockIdx.x;
    const int y    = blockIdx.y;
    const int b    = blockIdx.z;

    if (y == 6) {
        // rel_t[h][n][d] = f16(rel_h[h][d][n&31] + rel_w[h][d][n>>5])
        const int k    = b * 8 + bx;                    // 0..127
        const int idx0 = k * 2048 + threadIdx.x * 8;
        const int d0 = idx0 & 63;
        const int n  = (idx0 >> 6) & (Nn - 1);
        const int h  = idx0 >> 16;
        f16x8 w;
        #pragma unroll
        for (int u = 0; u < 8; u++) {
            const int hd = h * 64 + d0 + u;
            w[u] = (f16)(rel_h[hd * 32 + (n & 31)] + rel_w[hd * 32 + (n >> 5)]);
        }
        *(f16x8*)&rel_t[idx0] = w;
        return;
    }

    const int p    = y >> 1;
    const int half = y & 1;

    constexpr int ST = 40;
    __shared__ f16 Wt[128 * ST];    // [o 128][c 32]
    __shared__ f16 Xt[128 * ST];    // [n 128][c 32]

    const int t    = threadIdx.x;
    const int wave = t >> 6;
    const int lane = t & 63;
    const int l16  = lane & 15;
    const int quad = lane >> 4;
    const int wm   = wave >> 1;
    const int wsd  = wave & 1;

    const float* Wsel = (p == 0) ? Wq : (p == 1) ? Wk : Wv;

    f32x4 acc[4][4];
    #pragma unroll
    for (int mi = 0; mi < 4; mi++)
        #pragma unroll
        for (int ni = 0; ni < 4; ni++) acc[mi][ni] = (f32x4){0.f, 0.f, 0.f, 0.f};

    for (int c0 = 0; c0 < 256; c0 += 32) {
        // ---- global -> regs ----
        float4 wreg[4];
        float  xcol[2][8];
        #pragma unroll
        for (int rep = 0; rep < 4; rep++) {
            const int e  = t + rep * 256;
            const int r  = e >> 3;          // o row 0..127
            const int c4 = e & 7;           // float4 within 32-c chunk
            wreg[rep] = *(const float4*)
                &Wsel[(size_t)(half * 128 + r) * 256 + c0 + c4 * 4];
        }
        #pragma unroll
        for (int rep = 0; rep < 2; rep++) {
            const int e  = t + rep * 256;
            const int nn = e & 127;         // n within 128-tile
            const int c8 = e >> 7;          // 8-c group 0..3
            #pragma unroll
            for (int u = 0; u < 8; u++)
                xcol[rep][u] = x[((size_t)b * Cch + c0 + c8 * 8 + u) * Nn
                                 + bx * 128 + nn];
        }
        __syncthreads();   // prior MFMA reads of Wt/Xt complete

        // ---- regs -> LDS (cast) ----
        #pragma unroll
        for (int rep = 0; rep < 4; rep++) {
            const int e  = t + rep * 256;
            const int r  = e >> 3;
            const int c4 = e & 7;
            f16x4 wv;
            wv.x = (f16)wreg[rep].x; wv.y = (f16)wreg[rep].y;
            wv.z = (f16)wreg[rep].z; wv.w = (f16)wreg[rep].w;
            *(f16x4*)&Wt[r * ST + c4 * 4] = wv;
        }
        #pragma unroll
        for (int rep = 0; rep < 2; rep++) {
            const int e  = t + rep * 256;
            const int nn = e & 127;
            const int c8 = e >> 7;
            f16x8 xv;
            #pragma unroll
            for (int u = 0; u < 8; u++) xv[u] = (f16)xcol[rep][u];
            *(f16x8*)&Xt[nn * ST + c8 * 8] = xv;
        }
        __syncthreads();

        // ---- MFMA ----
        const f16* tf = (p < 2) ? Wt : Xt;
        const f16* ts = (p < 2) ? Xt : Wt;
        f16x8 af[4], bf[4];
        #pragma unroll
        for (int mi = 0; mi < 4; mi++)
            af[mi] = *(const f16x8*)&tf[(wm * 64 + mi * 16 + l16) * ST + quad * 8];
        #pragma unroll
        for (int ni = 0; ni < 4; ni++)
            bf[ni] = *(const f16x8*)&ts[(wsd * 64 + ni * 16 + l16) * ST + quad * 8];
        #pragma unroll
        for (int mi = 0; mi < 4; mi++)
            #pragma unroll
            for (int ni = 0; ni < 4; ni++)
                acc[mi][ni] = __builtin_amdgcn_mfma_f32_16x16x32_f16(
                    af[mi], bf[ni], acc[mi][ni], 0, 0, 0);
    }

    if (p < 2) {
        f16* yt = (p == 0) ? qt : kt;
        const float* bg = (p == 0) ? bq : bk;
        #pragma unroll
        for (int mi = 0; mi < 4; mi++) {
            const int o_in = half * 128 + wm * 64 + mi * 16 + quad * 4;
            const float4 b4 = *(const float4*)&bg[o_in];
            const int h = o_in >> 6;
            const int d = o_in & 63;
            #pragma unroll
            for (int ni = 0; ni < 4; ni++) {
                const int n = bx * 128 + wsd * 64 + ni * 16 + l16;
                f16x4 w;
                w.x = (f16)(acc[mi][ni][0] + b4.x);
                w.y = (f16)(acc[mi][ni][1] + b4.y);
                w.z = (f16)(acc[mi][ni][2] + b4.z);
                w.w = (f16)(acc[mi][ni][3] + b4.w);
                *(f16x4*)&yt[(((size_t)b * NH + h) * Nn + n) * Dh + d] = w;
            }
        }
    } else {
        #pragma unroll
        for (int ni = 0; ni < 4; ni++) {
            const int c  = half * 128 + wsd * 64 + ni * 16 + l16;
            const float bs = bv[c];
            #pragma unroll
            for (int mi = 0; mi < 4; mi++) {
                const int n = bx * 128 + wm * 64 + mi * 16 + quad * 4;
                f16x4 w;
                w.x = (f16)(acc[mi][ni][0] + bs);
                w.y = (f16)(acc[mi][ni][1] + bs);
                w.z = (f16)(acc[mi][ni][2] + bs);
                w.w = (f16)(acc[mi][ni][3] + bs);
                *(f16x4*)&vb[((size_t)b * Cch + c) * Nn + n] = w;
            }
        }
    }
}

// ---------------------------------------------------------------------------
// Flash attention, fp16 MFMA.
// ROUND 9: LDS-pipe desaturation. Counter arithmetic showed ~85% LDS-pipe
// utilization (vs MFMA 17% / VALU 34% / HBM 6%) — staging reads dominate.
// Change: K|Q and V MFMA B-fragments are loaded DIRECTLY FROM GLOBAL
// (L1/L2-resident via the XCD-bijective mapping; 16B/lane, 64B/row segments).
//  - Ka_s / v_s staging and BOTH per-tile barriers deleted: j-loop is
//    barrier-free, waves slip freely (latency self-hides).
//  - ~348 of ~521 LDS cyc/wave/tile move to the idle VMEM pipe.
//  - Address derivation replicates the old swizzled-LDS read semantics:
//      bb(js,k) = (k<2 ? ktb : qtb)[(j0+js*16+l16)*64 + ((k*4+quad)&7)*8]
//      vv(ds,ks)= vbb[(ds*16+l16)*1024 + j0 + (ks*4+quad)*8]
//  - Pt_s (wave-private P transpose) and Qa staging unchanged. LDS 48 KB.
// grid = (512), block = 512.
// ---------------------------------------------------------------------------
__global__ __launch_bounds__(512, 4) void attn_mfma(
    const f16* __restrict__ qt, const f16* __restrict__ kt,
    const f16* __restrict__ relt, const f16* __restrict__ vb,
    float* __restrict__ out)
{
    // XCD-bijective decode: all blocks with the same bh share an XCD
    const int bid = blockIdx.x;
    const int bh  = bid & 63;         // b*4 + h
    const int i0  = (bid >> 6) * 128;
    const int h   = bh & 3;
    const int b   = bh >> 2;

    const f16* qtb = qt  + (size_t)bh * Nn * Dh;            // [n][64]
    const f16* ktb = kt  + (size_t)bh * Nn * Dh;            // [n][64]
    const f16* rlt = relt + (size_t)h * Nn * Dh;            // [n][64]
    const f16* vbb = vb  + (size_t)(b * Cch + h * Dh) * Nn; // [d][1024]

    // XOR-swizzled Qa: elem(row,col) at row*128 + ((col>>3 ^ (row&7))<<3)+(col&7)
    __shared__ f16 Qa_s[128 * 128];  // 32 KB  [i][128: q|rel]
    __shared__ f16 Pt_s[128 * 64];   // 16 KB  [i][j]

    const int t    = threadIdx.x;
    const int wave = t >> 6;         // 0..7
    const int lane = t & 63;
    const int l16  = lane & 15;
    const int quad = lane >> 4;

    // ---- stage Qa = [q | rel]: 128 rows x 128 f16, swizzled ----
    #pragma unroll
    for (int rep = 0; rep < 4; rep++) {
        const int e   = t + rep * 512;
        const int row = e >> 4;
        const int c8  = e & 15;
        const f16* src = (c8 < 8)
            ? &qtb[(size_t)(i0 + row) * Dh + c8 * 8]
            : &rlt[(size_t)(i0 + row) * Dh + (c8 - 8) * 8];
        *(f16x8*)&Qa_s[(row << 7) + ((c8 ^ (row & 7)) << 3)] = *(const f16x8*)src;
    }
    __syncthreads();

    // ---- hoist Qa A-fragments (j-invariant): 1 m-subtile x 4 k-slices ----
    f16x8 af[4];
    {
        const int row = wave * 16 + l16;
        #pragma unroll
        for (int k = 0; k < 4; k++)
            af[k] = *(const f16x8*)
                &Qa_s[(row << 7) + ((((k << 2) + quad) ^ (row & 7)) << 3)];
    }

    f16x8 ones;
    #pragma unroll
    for (int u = 0; u < 8; u++) ones[u] = (f16)1.0f;

    f32x4 Of[4], Ol;
    float m_r[4];
    Ol = (f32x4){0.f, 0.f, 0.f, 0.f};
    #pragma unroll
    for (int ds = 0; ds < 4; ds++) Of[ds] = (f32x4){0.f, 0.f, 0.f, 0.f};
    #pragma unroll
    for (int r = 0; r < 4; r++) m_r[r] = -1e30f;

    for (int j0 = 0; j0 < Nn; j0 += 64) {
        // ---- S = Qa·[K|Q]^T : 16 rows x 64 cols, K=128; B-frags from global ----
        f32x4 Sf[4];
        #pragma unroll
        for (int js = 0; js < 4; js++) Sf[js] = (f32x4){0.f, 0.f, 0.f, 0.f};
        #pragma unroll
        for (int k = 0; k < 4; k++) {
            const f16* basek = (k < 2) ? ktb : qtb;
            const int  colk  = ((k & 1) * 4 + quad) * 8;   // (k*4+quad)&7 * 8
            f16x8 bb[4];
            #pragma unroll
            for (int js = 0; js < 4; js++) {
                const int row = j0 + js * 16 + l16;
                bb[js] = *(const f16x8*)&basek[(size_t)row * Dh + colk];
            }
            #pragma unroll
            for (int js = 0; js < 4; js++)
                Sf[js] = __builtin_amdgcn_mfma_f32_16x16x32_f16(
                    af[k], bb[js], Sf[js], 0, 0, 0);
        }

        // ---- online softmax (max tree only; sums via MFMA ones) ----
        #pragma unroll
        for (int r = 0; r < 4; r++) {
            float tm = fmaxf(fmaxf(Sf[0][r], Sf[1][r]),
                             fmaxf(Sf[2][r], Sf[3][r]));
            tm = fmaxf(tm, __shfl_xor(tm, 1));
            tm = fmaxf(tm, __shfl_xor(tm, 2));
            tm = fmaxf(tm, __shfl_xor(tm, 4));
            tm = fmaxf(tm, __shfl_xor(tm, 8));
            const float mnew  = fmaxf(m_r[r], tm);
            const float alpha = __expf(m_r[r] - mnew);
            m_r[r] = mnew;

            const int row = wave * 16 + quad * 4 + r;
            const int rx  = row & 7;
            #pragma unroll
            for (int js = 0; js < 4; js++) {
                const float p = __expf(Sf[js][r] - mnew);
                const int col = js * 16 + l16;
                Pt_s[(row << 6) + (((col >> 3) ^ rx) << 3) + (col & 7)] = (f16)p;
            }
            #pragma unroll
            for (int ds = 0; ds < 4; ds++) Of[ds][r] *= alpha;
            Ol[r] *= alpha;
        }
        // Pt rows are wave-private: in-wave LDS ordering, no barrier

        // ---- O += P·V^T (K=64); l += P·1 ; V-frags from global ----
        #pragma unroll
        for (int ks = 0; ks < 2; ks++) {
            const int prow = wave * 16 + l16;
            f16x8 pa = *(const f16x8*)
                &Pt_s[(prow << 6) + ((((ks << 2) + quad) ^ (prow & 7)) << 3)];
            const int colv = j0 + (ks * 4 + quad) * 8;
            #pragma unroll
            for (int ds = 0; ds < 4; ds++) {
                const int vrow = ds * 16 + l16;
                f16x8 vv = *(const f16x8*)&vbb[(size_t)vrow * Nn + colv];
                Of[ds] = __builtin_amdgcn_mfma_f32_16x16x32_f16(
                    pa, vv, Of[ds], 0, 0, 0);
            }
            Ol = __builtin_amdgcn_mfma_f32_16x16x32_f16(
                pa, ones, Ol, 0, 0, 0);
        }
    }

    // ---- epilogue ----
    #pragma unroll
    for (int r = 0; r < 4; r++) {
        const float inv = 1.0f / Ol[r];
        const int i = i0 + wave * 16 + quad * 4 + r;
        #pragma unroll
        for (int ds = 0; ds < 4; ds++) {
            const int d = ds * 16 + l16;
            out[((size_t)(b * Cch + h * Dh + d)) * Nn + i] = Of[ds][r] * inv;
        }
    }
}

// ---------------------------------------------------------------------------
extern "C" void kernel_launch(void* const* d_in, const int* in_sizes, int n_in,
                              void* d_out, int out_size, void* d_ws, size_t ws_size,
                              hipStream_t stream)
{
    const float* x     = (const float*)d_in[0];
    const float* Wq    = (const float*)d_in[1];
    const float* bq    = (const float*)d_in[2];
    const float* Wk    = (const float*)d_in[3];
    const float* bk    = (const float*)d_in[4];
    const float* Wv    = (const float*)d_in[5];
    const float* bv    = (const float*)d_in[6];
    const float* rel_h = (const float*)d_in[7];
    const float* rel_w = (const float*)d_in[8];

    f16* ws = (f16*)d_ws;
    const size_t SZQ = (size_t)Bb * NH * Nn * Dh;    // 4 Mi elems
    f16* qt   = ws;                                  // 8 MB
    f16* kt   = ws + SZQ;                            // 8 MB
    f16* vbuf = ws + 2 * SZQ;                        // 8 MB
    f16* relt = ws + 3 * SZQ;                        // 0.5 MB

    gemm_qkv<<<dim3(Nn / 128, 7, Bb), 256, 0, stream>>>(
        x, Wq, Wk, Wv, bq, bk, bv, rel_h, rel_w, qt, kt, vbuf, relt);
    attn_mfma<<<dim3(512), 512, 0, stream>>>(
        qt, kt, relt, vbuf, (float*)d_out);
}